// Round 1
// 455.954 us; speedup vs baseline: 1.1309x; 1.1309x over previous
//
#include <hip/hip_runtime.h>
#include <cstdint>

typedef unsigned short u16t;
typedef float v4f __attribute__((ext_vector_type(4)));
typedef short v8s __attribute__((ext_vector_type(8)));

#define HIDDEN 2048
#define NHEAD 16
#define HDIM 128
#define SEQ 2048
#define BATCH 2
#define MROWS (BATCH * SEQ) /* 4096 */

__device__ __forceinline__ float bf2f(u16t u) {
  return __builtin_bit_cast(float, (uint32_t)((uint32_t)u << 16));
}
__device__ __forceinline__ u16t f2bf(float f) {
  uint32_t u = __builtin_bit_cast(uint32_t, f);
  u += 0x7FFFu + ((u >> 16) & 1u);
  return (u16t)(u >> 16);
}
__device__ __forceinline__ ushort4 f2bf4(float4 v) {
  ushort4 r;
  r.x = f2bf(v.x); r.y = f2bf(v.y); r.z = f2bf(v.z); r.w = f2bf(v.w);
  return r;
}

// async global->LDS, 16B per lane. LDS dest must be wave-uniform base + lane*16.
__device__ __forceinline__ void gld_lds16(const u16t* g, u16t* l) {
  __builtin_amdgcn_global_load_lds(
      (const __attribute__((address_space(1))) uint32_t*)g,
      (__attribute__((address_space(3))) uint32_t*)l, 16, 0, 0);
}

// ---------------------------------------------------------------------------
// fp32 -> bf16 elementwise convert (8 elems/thread)
// ---------------------------------------------------------------------------
__global__ __launch_bounds__(256) void cvt_bf16(const float* __restrict__ src,
                                                u16t* __restrict__ dst, int n8) {
  int i = blockIdx.x * 256 + threadIdx.x;
  if (i < n8) {
    float4 a = ((const float4*)src)[2 * i];
    float4 b = ((const float4*)src)[2 * i + 1];
    union { ushort4 h[2]; uint4 u; } pk;
    pk.h[0] = f2bf4(a);
    pk.h[1] = f2bf4(b);
    ((uint4*)dst)[i] = pk.u;
  }
}

// All four weight matrices in one launch (each HIDDEN*HIDDEN, n8 = 2^19 each).
__global__ __launch_bounds__(256) void cvt_bf16_w4(
    const float* __restrict__ s0, const float* __restrict__ s1,
    const float* __restrict__ s2, const float* __restrict__ s3,
    u16t* __restrict__ d0, u16t* __restrict__ d1,
    u16t* __restrict__ d2, u16t* __restrict__ d3) {
  int i = blockIdx.x * 256 + threadIdx.x;
  int sel = i >> 19;          // WN8 == 2^19
  int j = i & 0x7FFFF;
  const float* src = (sel == 0) ? s0 : (sel == 1) ? s1 : (sel == 2) ? s2 : s3;
  u16t* dst = (sel == 0) ? d0 : (sel == 1) ? d1 : (sel == 2) ? d2 : d3;
  float4 a = ((const float4*)src)[2 * j];
  float4 b = ((const float4*)src)[2 * j + 1];
  union { ushort4 h[2]; uint4 u; } pk;
  pk.h[0] = f2bf4(a);
  pk.h[1] = f2bf4(b);
  ((uint4*)dst)[j] = pk.u;
}

// ---------------------------------------------------------------------------
// GEMM (m97 structure): C[m,n] = sum_k A[m,k] * B[n,k]   (unchanged)
// ---------------------------------------------------------------------------
template <int B_BF16, int OUT_F32>
__global__ __launch_bounds__(256) void gemm_a16(const u16t* __restrict__ A,
                                                const void* __restrict__ Bp,
                                                void* __restrict__ Cp) {
  __shared__ u16t As[128 * 32];
  __shared__ u16t Bs[128 * 32];

  const int n0 = blockIdx.x * 128;
  const int m0 = blockIdx.y * 128;
  const int t = threadIdx.x;
  const int lane = t & 63;
  const int w = t >> 6;
  const int wm = w & 1;
  const int wn = w >> 1;
  const int l15 = lane & 15;
  const int quad = lane >> 4;

  v4f acc[4][4];
#pragma unroll
  for (int i = 0; i < 4; ++i)
#pragma unroll
    for (int j = 0; j < 4; ++j) acc[i][j] = (v4f){0.f, 0.f, 0.f, 0.f};

  for (int kb = 0; kb < HIDDEN; kb += 32) {
#pragma unroll
    for (int j = 0; j < 2; ++j) {
      int idx = t + j * 256;
      int row = idx >> 2;
      int ch = (idx & 3) * 8;
      gld_lds16(&A[(size_t)(m0 + row) * HIDDEN + kb + ch], &As[idx * 8]);
      if (B_BF16)
        gld_lds16(&((const u16t*)Bp)[(size_t)(n0 + row) * HIDDEN + kb + ch], &Bs[idx * 8]);
    }
    if (!B_BF16) {
      const float* B = (const float*)Bp;
#pragma unroll
      for (int j = 0; j < 4; ++j) {
        int idx = t + j * 256;
        int row = idx >> 3;
        int c4 = (idx & 7) * 4;
        float4 bv = *(const float4*)&B[(size_t)(n0 + row) * HIDDEN + kb + c4];
        *(ushort4*)&Bs[row * 32 + c4] = f2bf4(bv);
      }
    }
    __syncthreads();

    v8s af[4], bf[4];
#pragma unroll
    for (int mt = 0; mt < 4; ++mt)
      af[mt] = *(const v8s*)&As[(wm * 64 + mt * 16 + l15) * 32 + quad * 8];
#pragma unroll
    for (int nt = 0; nt < 4; ++nt)
      bf[nt] = *(const v8s*)&Bs[(wn * 64 + nt * 16 + l15) * 32 + quad * 8];

#pragma unroll
    for (int mt = 0; mt < 4; ++mt)
#pragma unroll
      for (int nt = 0; nt < 4; ++nt)
        acc[mt][nt] = __builtin_amdgcn_mfma_f32_16x16x32_bf16(af[mt], bf[nt], acc[mt][nt], 0, 0, 0);
    __syncthreads();
  }

#pragma unroll
  for (int mt = 0; mt < 4; ++mt) {
#pragma unroll
    for (int nt = 0; nt < 4; ++nt) {
      int col = n0 + wn * 64 + nt * 16 + l15;
#pragma unroll
      for (int r = 0; r < 4; ++r) {
        int row = m0 + wm * 64 + mt * 16 + quad * 4 + r;
        if (OUT_F32)
          ((float*)Cp)[(size_t)row * HIDDEN + col] = acc[mt][nt][r];
        else
          ((u16t*)Cp)[(size_t)row * HIDDEN + col] = f2bf(acc[mt][nt][r]);
      }
    }
  }
}

// ---------------------------------------------------------------------------
// V-projection GEMM with TRANSPOSED bf16 output vt[n][m]   (unchanged)
// ---------------------------------------------------------------------------
template <int B_BF16>
__global__ __launch_bounds__(256) void gemm_vt(const u16t* __restrict__ A,
                                               const void* __restrict__ Bp,
                                               u16t* __restrict__ VtOut) {
  __shared__ u16t As[128 * 32];
  __shared__ u16t Bs[128 * 32];
  __shared__ u16t Ct[128 * 136];

  const int n0 = blockIdx.x * 128;
  const int m0 = blockIdx.y * 128;
  const int t = threadIdx.x;
  const int lane = t & 63;
  const int w = t >> 6;
  const int wm = w & 1;
  const int wn = w >> 1;
  const int l15 = lane & 15;
  const int quad = lane >> 4;

  v4f acc[4][4];
#pragma unroll
  for (int i = 0; i < 4; ++i)
#pragma unroll
    for (int j = 0; j < 4; ++j) acc[i][j] = (v4f){0.f, 0.f, 0.f, 0.f};

  for (int kb = 0; kb < HIDDEN; kb += 32) {
#pragma unroll
    for (int j = 0; j < 2; ++j) {
      int idx = t + j * 256;
      int row = idx >> 2;
      int ch = (idx & 3) * 8;
      gld_lds16(&A[(size_t)(m0 + row) * HIDDEN + kb + ch], &As[idx * 8]);
      if (B_BF16)
        gld_lds16(&((const u16t*)Bp)[(size_t)(n0 + row) * HIDDEN + kb + ch], &Bs[idx * 8]);
    }
    if (!B_BF16) {
      const float* B = (const float*)Bp;
#pragma unroll
      for (int j = 0; j < 4; ++j) {
        int idx = t + j * 256;
        int row = idx >> 3;
        int c4 = (idx & 7) * 4;
        float4 bv = *(const float4*)&B[(size_t)(n0 + row) * HIDDEN + kb + c4];
        *(ushort4*)&Bs[row * 32 + c4] = f2bf4(bv);
      }
    }
    __syncthreads();

    v8s af[4], bf[4];
#pragma unroll
    for (int mt = 0; mt < 4; ++mt)
      af[mt] = *(const v8s*)&As[(wm * 64 + mt * 16 + l15) * 32 + quad * 8];
#pragma unroll
    for (int nt = 0; nt < 4; ++nt)
      bf[nt] = *(const v8s*)&Bs[(wn * 64 + nt * 16 + l15) * 32 + quad * 8];

#pragma unroll
    for (int mt = 0; mt < 4; ++mt)
#pragma unroll
      for (int nt = 0; nt < 4; ++nt)
        acc[mt][nt] = __builtin_amdgcn_mfma_f32_16x16x32_bf16(af[mt], bf[nt], acc[mt][nt], 0, 0, 0);
    __syncthreads();
  }

#pragma unroll
  for (int mt = 0; mt < 4; ++mt)
#pragma unroll
    for (int nt = 0; nt < 4; ++nt)
#pragma unroll
      for (int r = 0; r < 4; ++r)
        Ct[(wn * 64 + nt * 16 + l15) * 136 + (wm * 64 + mt * 16 + quad * 4 + r)] =
            f2bf(acc[mt][nt][r]);
  __syncthreads();

#pragma unroll
  for (int j = 0; j < 8; ++j) {
    int idx = t + j * 256;
    int nl = idx >> 4;
    int mc = idx & 15;
    *(uint4*)&VtOut[(size_t)(n0 + nl) * MROWS + m0 + mc * 8] =
        *(const uint4*)&Ct[nl * 136 + mc * 8];
  }
}

// ---------------------------------------------------------------------------
// RoPE in-place on q and k (bf16, [m][h*128+d])   (unchanged)
// ---------------------------------------------------------------------------
__global__ __launch_bounds__(256) void rope_k(u16t* __restrict__ q, u16t* __restrict__ k) {
  int idx = blockIdx.x * 256 + threadIdx.x;
  int i = idx & 63;
  int h = (idx >> 6) & (NHEAD - 1);
  int m = idx >> 10;
  int s = m & (SEQ - 1);
  float inv = __expf(-(float)i * 0.14391156831212787f);
  float th = (float)s * inv;
  float sn, cs;
  __sincosf(th, &sn, &cs);
  size_t base = (size_t)m * HIDDEN + h * HDIM + i;
  {
    float a = bf2f(q[base]), b = bf2f(q[base + 64]);
    q[base] = f2bf(a * cs - b * sn);
    q[base + 64] = f2bf(b * cs + a * sn);
  }
  {
    float a = bf2f(k[base]), b = bf2f(k[base + 64]);
    k[base] = f2bf(a * cs - b * sn);
    k[base + 64] = f2bf(b * cs + a * sn);
  }
}

// ---------------------------------------------------------------------------
// Flash attention v3: XOR-swizzled LDS (T2), async reg-prefetch staging (T14),
// double-buffered K/V -> 1 barrier per kv-step, mask hoisted to last 2 steps.
// LDS layout (u16 units): Ks0[64][128] | Vs0[128][64] | Ks1 | Vs1 | Ps[128][64]
//   all power-of-2 row strides; swizzle: elem ^= (row&7)*8  (16B-chunk XOR).
// 256 blocks x 512 thr (grid-limited 1 block/CU; LDS 80KB is free).
// ---------------------------------------------------------------------------
__global__ __launch_bounds__(512) void flash2(const u16t* __restrict__ Q,
                                              const u16t* __restrict__ K,
                                              const u16t* __restrict__ Vt,
                                              u16t* __restrict__ O) {
  __shared__ u16t smem[40960];  // 80 KB
  u16t* Ps = smem + 32768;

  const int a = blockIdx.x;
  const int bh = blockIdx.y;
  const int b = bh >> 4;
  const int h = bh & 15;
  const size_t rowb = (size_t)b * SEQ;
  const u16t* vtg = Vt + (size_t)h * HDIM * MROWS + (size_t)b * SEQ;

  const int t = threadIdx.x;
  const int lane = t & 63;
  const int w = t >> 6;
  const int l15 = lane & 15;
  const int quad = lane >> 4;
  const int l7 = l15 & 7;
  const float C2 = 0.12751743f;
  const float NEG = -3.0e38f;

  // staging geometry (constant per thread)
  const int krow = t >> 4;            // K rows krow, krow+32; 16 chunks/row
  const int kch = (t & 15) * 8;
  const int vrow = t >> 3;            // V rows vrow, vrow+64; 8 chunks/row
  const int vch = (t & 7) * 8;
  const int kx = kch ^ ((krow & 7) * 8);   // (krow+32)&7 == krow&7
  const int vx = vch ^ ((vrow & 7) * 8);   // (vrow+64)&7 == vrow&7
  const u16t* Kgb = &K[(rowb + krow) * HIDDEN + h * HDIM + kch];
  const u16t* Vgb = vtg + (size_t)vrow * MROWS + vch;

  for (int half = 0; half < 2; ++half) {
    const int qt = half ? (15 - a) : a;
    const int q0 = qt * 128;
    const int nsteps = 2 * (qt + 1);

    // prologue: issue kv-tile 0 loads (latency hides under Q staging)
    uint4 ck0 = *(const uint4*)Kgb;
    uint4 ck1 = *(const uint4*)(Kgb + 32 * HIDDEN);
    uint4 cv0 = *(const uint4*)Vgb;
    uint4 cv1 = *(const uint4*)(Vgb + (size_t)64 * MROWS);

    // stage Q (transient, stride 136), read fragments
#pragma unroll
    for (int j = 0; j < 4; ++j) {
      int idx = t + j * 512;
      int row = idx >> 4;
      int ch = (idx & 15) * 8;
      *(uint4*)&smem[row * 136 + ch] =
          *(const uint4*)&Q[(rowb + q0 + row) * HIDDEN + h * HDIM + ch];
    }
    __syncthreads();
    v8s qf[4];
#pragma unroll
    for (int ks = 0; ks < 4; ++ks)
      qf[ks] = *(const v8s*)&smem[(w * 16 + l15) * 136 + ks * 32 + quad * 8];
    __syncthreads();

    float mi[4], li[4];
    v4f o[8];
#pragma unroll
    for (int r = 0; r < 4; ++r) { mi[r] = NEG; li[r] = 0.f; }
#pragma unroll
    for (int nt = 0; nt < 8; ++nt) o[nt] = (v4f){0.f, 0.f, 0.f, 0.f};

    for (int kt = 0; kt < nsteps; ++kt) {
      u16t* Kb = smem + (kt & 1) * 16384;
      u16t* Vb = Kb + 8192;
      // write current tile to LDS (swizzled), then issue next-tile loads
      *(uint4*)&Kb[krow * 128 + kx] = ck0;
      *(uint4*)&Kb[(krow + 32) * 128 + kx] = ck1;
      *(uint4*)&Vb[vrow * 64 + vx] = cv0;
      *(uint4*)&Vb[(vrow + 64) * 64 + vx] = cv1;
      if (kt + 1 < nsteps) {
        const int kv1 = (kt + 1) * 64;
        const u16t* kg = Kgb + (size_t)kv1 * HIDDEN;
        ck0 = *(const uint4*)kg;
        ck1 = *(const uint4*)(kg + 32 * HIDDEN);
        const u16t* vg = Vgb + kv1;
        cv0 = *(const uint4*)vg;
        cv1 = *(const uint4*)(vg + (size_t)64 * MROWS);
      }
      __syncthreads();  // buf[kt&1] ready; buf[kt&1] consumers of step kt-2 done

      const int kv0 = kt * 64;
      // QK^T
      v4f sc[4];
#pragma unroll
      for (int nt = 0; nt < 4; ++nt) {
        sc[nt] = (v4f){0.f, 0.f, 0.f, 0.f};
#pragma unroll
        for (int ks = 0; ks < 4; ++ks) {
          v8s kf = *(const v8s*)&Kb[(nt * 16 + l15) * 128 +
                                    ((ks * 32 + quad * 8) ^ (l7 * 8))];
          sc[nt] = __builtin_amdgcn_mfma_f32_16x16x32_bf16(qf[ks], kf, sc[nt], 0, 0, 0);
        }
      }

      const bool mm = (kv0 + 64 > q0);  // uniform: only the last 2 steps mask
#pragma unroll
      for (int r = 0; r < 4; ++r) {
        float sv[4];
#pragma unroll
        for (int nt = 0; nt < 4; ++nt) sv[nt] = sc[nt][r];
        if (mm) {
          int row_g = q0 + w * 16 + quad * 4 + r;
#pragma unroll
          for (int nt = 0; nt < 4; ++nt)
            if (kv0 + nt * 16 + l15 > row_g) sv[nt] = NEG;
        }
        float rm = fmaxf(fmaxf(sv[0], sv[1]), fmaxf(sv[2], sv[3]));
#pragma unroll
        for (int off = 1; off < 16; off <<= 1) rm = fmaxf(rm, __shfl_xor(rm, off));
        float mn = fmaxf(mi[r], rm);
        float alpha = exp2f((mi[r] - mn) * C2);
        float ps = 0.f;
        u16t pb[4];
#pragma unroll
        for (int nt = 0; nt < 4; ++nt) {
          float p = exp2f((sv[nt] - mn) * C2);
          ps += p;
          pb[nt] = f2bf(p);
        }
#pragma unroll
        for (int off = 1; off < 16; off <<= 1) ps += __shfl_xor(ps, off);
        li[r] = li[r] * alpha + ps;
        mi[r] = mn;
#pragma unroll
        for (int nt = 0; nt < 8; ++nt) o[nt][r] *= alpha;
        int rowp = w * 16 + quad * 4 + r;
        int psw = (rowp & 7) * 8;
#pragma unroll
        for (int nt = 0; nt < 4; ++nt)
          Ps[rowp * 64 + ((nt * 16 + l15) ^ psw)] = pb[nt];
      }

      // PV (Ps round-trip is same-wave; lgkmcnt ordering suffices)
#pragma unroll
      for (int ks = 0; ks < 2; ++ks) {
        v8s pf = *(const v8s*)&Ps[(w * 16 + l15) * 64 +
                                  ((ks * 32 + quad * 8) ^ (l7 * 8))];
#pragma unroll
        for (int nt = 0; nt < 8; ++nt) {
          v8s vf = *(const v8s*)&Vb[(nt * 16 + l15) * 64 +
                                    ((ks * 32 + quad * 8) ^ (l7 * 8))];
          o[nt] = __builtin_amdgcn_mfma_f32_16x16x32_bf16(pf, vf, o[nt], 0, 0, 0);
        }
      }
    }

#pragma unroll
    for (int r = 0; r < 4; ++r) {
      float inv = 1.0f / li[r];
      size_t row = rowb + q0 + w * 16 + quad * 4 + r;
#pragma unroll
      for (int nt = 0; nt < 8; ++nt)
        O[row * HIDDEN + h * HDIM + nt * 16 + l15] = f2bf(o[nt][r] * inv);
    }
    __syncthreads();  // protect smem before next half's Q staging
  }
}

// ---------------------------------------------------------------------------
extern "C" void kernel_launch(void* const* d_in, const int* in_sizes, int n_in,
                              void* d_out, int out_size, void* d_ws, size_t ws_size,
                              hipStream_t stream) {
  const float* X = (const float*)d_in[0];
  const float* Wq = (const float*)d_in[3];
  const float* Wk = (const float*)d_in[4];
  const float* Wv = (const float*)d_in[5];
  const float* Wo = (const float*)d_in[6];
  float* out = (float*)d_out;

  char* wsb = (char*)d_ws;
  const size_t MB = 1024 * 1024;
  u16t* xb = (u16t*)(wsb + 0 * MB);    // 16 MB, dead after QKV gemms
  u16t* q = (u16t*)(wsb + 16 * MB);    // 16 MB
  u16t* k = (u16t*)(wsb + 32 * MB);    // 16 MB
  u16t* vt = (u16t*)(wsb + 48 * MB);   // 16 MB
  u16t* a = xb;                        // flash out aliases xb (xb dead by then)

  dim3 blk(256);
  dim3 gg(HIDDEN / 128, MROWS / 128);  // (16, 32)
  dim3 fg(8, BATCH * NHEAD);
  const int XN8 = MROWS * HIDDEN / 8;   // 1M
  const int WN8 = HIDDEN * HIDDEN / 8;  // 512K (= 2^19)

  cvt_bf16<<<(XN8 + 255) / 256, blk, 0, stream>>>(X, xb, XN8);

  if (ws_size >= 96 * MB) {
    u16t* wqb = (u16t*)(wsb + 64 * MB);
    u16t* wkb = (u16t*)(wsb + 72 * MB);
    u16t* wvb = (u16t*)(wsb + 80 * MB);
    u16t* wob = (u16t*)(wsb + 88 * MB);
    cvt_bf16_w4<<<(4 * WN8) / 256, blk, 0, stream>>>(Wq, Wk, Wv, Wo, wqb, wkb, wvb, wob);

    gemm_a16<1, 0><<<gg, blk, 0, stream>>>(xb, wqb, q);
    gemm_a16<1, 0><<<gg, blk, 0, stream>>>(xb, wkb, k);
    gemm_vt<1><<<gg, blk, 0, stream>>>(xb, wvb, vt);
    rope_k<<<(MROWS * NHEAD * 64) / 256, blk, 0, stream>>>(q, k);
    flash2<<<fg, dim3(512), 0, stream>>>(q, k, vt, a);
    gemm_a16<1, 1><<<gg, blk, 0, stream>>>(a, wob, out);
  } else {
    gemm_a16<0, 0><<<gg, blk, 0, stream>>>(xb, Wq, q);
    gemm_a16<0, 0><<<gg, blk, 0, stream>>>(xb, Wk, k);
    gemm_vt<0><<<gg, blk, 0, stream>>>(xb, Wv, vt);
    rope_k<<<(MROWS * NHEAD * 64) / 256, blk, 0, stream>>>(q, k);
    flash2<<<fg, dim3(512), 0, stream>>>(q, k, vt, a);
    gemm_a16<0, 1><<<gg, blk, 0, stream>>>(a, Wo, out);
  }
}

// Round 3
// 424.272 us; speedup vs baseline: 1.2154x; 1.0747x over previous
//
#include <hip/hip_runtime.h>
#include <cstdint>

typedef unsigned short u16t;
typedef float v4f __attribute__((ext_vector_type(4)));
typedef short v8s __attribute__((ext_vector_type(8)));

#define HIDDEN 2048
#define NHEAD 16
#define HDIM 128
#define SEQ 2048
#define BATCH 2
#define MROWS (BATCH * SEQ) /* 4096 */

__device__ __forceinline__ float bf2f(u16t u) {
  return __builtin_bit_cast(float, (uint32_t)((uint32_t)u << 16));
}
__device__ __forceinline__ u16t f2bf(float f) {
  uint32_t u = __builtin_bit_cast(uint32_t, f);
  u += 0x7FFFu + ((u >> 16) & 1u);
  return (u16t)(u >> 16);
}
__device__ __forceinline__ ushort4 f2bf4(float4 v) {
  ushort4 r;
  r.x = f2bf(v.x); r.y = f2bf(v.y); r.z = f2bf(v.z); r.w = f2bf(v.w);
  return r;
}

// async global->LDS, 16B per lane. LDS dest must be wave-uniform base + lane*16.
__device__ __forceinline__ void gld_lds16(const u16t* g, u16t* l) {
  __builtin_amdgcn_global_load_lds(
      (const __attribute__((address_space(1))) uint32_t*)g,
      (__attribute__((address_space(3))) uint32_t*)l, 16, 0, 0);
}

// ---------------------------------------------------------------------------
// fp32 -> bf16 elementwise convert (8 elems/thread)
// ---------------------------------------------------------------------------
__global__ __launch_bounds__(256) void cvt_bf16(const float* __restrict__ src,
                                                u16t* __restrict__ dst, int n8) {
  int i = blockIdx.x * 256 + threadIdx.x;
  if (i < n8) {
    float4 a = ((const float4*)src)[2 * i];
    float4 b = ((const float4*)src)[2 * i + 1];
    union { ushort4 h[2]; uint4 u; } pk;
    pk.h[0] = f2bf4(a);
    pk.h[1] = f2bf4(b);
    ((uint4*)dst)[i] = pk.u;
  }
}

// All four weight matrices in one launch (each HIDDEN*HIDDEN, n8 = 2^19 each).
__global__ __launch_bounds__(256) void cvt_bf16_w4(
    const float* __restrict__ s0, const float* __restrict__ s1,
    const float* __restrict__ s2, const float* __restrict__ s3,
    u16t* __restrict__ d0, u16t* __restrict__ d1,
    u16t* __restrict__ d2, u16t* __restrict__ d3) {
  int i = blockIdx.x * 256 + threadIdx.x;
  int sel = i >> 19;          // WN8 == 2^19
  int j = i & 0x7FFFF;
  const float* src = (sel == 0) ? s0 : (sel == 1) ? s1 : (sel == 2) ? s2 : s3;
  u16t* dst = (sel == 0) ? d0 : (sel == 1) ? d1 : (sel == 2) ? d2 : d3;
  float4 a = ((const float4*)src)[2 * j];
  float4 b = ((const float4*)src)[2 * j + 1];
  union { ushort4 h[2]; uint4 u; } pk;
  pk.h[0] = f2bf4(a);
  pk.h[1] = f2bf4(b);
  ((uint4*)dst)[j] = pk.u;
}

// ---------------------------------------------------------------------------
// Pipelined GEMM: C[m,n] = sum_k A[m,k] * B[n,k], bf16 in, acc fp32.
// BM=256 BN=128 BK=64, 512 thr = 8 waves (2M x 4N), per-wave 128x32 out.
// Grid (N/128, M/256) = (16,16) = 256 WGs = 1/CU.
// 3 LDS buffers (tile kt uses buf kt%3; prefetch depth 2), counted vmcnt(6)
// (never drained to 0 in steady state), __builtin s_barrier, T2 XOR swizzle
// (pre-swizzled global src -> linear gld_lds dest, swizzled ds_read),
// T5 setprio around MFMA clusters.
// OUT: 0 = bf16 C[m][n], 1 = f32 C[m][n], 2 = bf16 transposed C[n][m] (for Vt).
// ---------------------------------------------------------------------------
template <int OUT>
__global__ __launch_bounds__(512) void gemm8p(const u16t* __restrict__ A,
                                              const u16t* __restrict__ B,
                                              void* __restrict__ Cp) {
  // As: 3 x [256][64] u16 = 49152 ; Bs: 3 x [128][64] u16 = 24576 ; 144 KB total
  __shared__ u16t lds[73728];

  const int n0 = blockIdx.x * 128;
  const int m0 = blockIdx.y * 256;
  const int t = threadIdx.x;
  const int lane = t & 63;
  const int w = t >> 6;        // 0..7
  const int wm = w >> 2;       // 0..1  (M half)
  const int wn = w & 3;        // 0..3  (N quarter)
  const int l15 = lane & 15;
  const int quad = lane >> 4;
  const int l7 = l15 & 7;

  // staging lane geometry: chunk = 8 rows x 64 cols (1KB), lane covers 16B.
  // LDS linear; global source col pre-swizzled so read-side XOR decodes it.
  const int lrow = lane >> 3;                 // 0..7 row within chunk
  const int lcol8 = ((lane & 7) ^ lrow) * 8;  // swizzled col (u16 units)
  const u16t* Ag = A + (size_t)(m0 + w * 32 + lrow) * HIDDEN + lcol8;
  const u16t* Bg = B + (size_t)(n0 + w * 16 + lrow) * HIDDEN + lcol8;

  // swizzled read cols for the two K=32 slices (u16 units)
  const int ca0 = (quad * 8) ^ (l7 * 8);
  const int ca1 = (32 + quad * 8) ^ (l7 * 8);

  v4f acc[8][2];
#pragma unroll
  for (int i = 0; i < 8; ++i)
#pragma unroll
    for (int j = 0; j < 2; ++j) acc[i][j] = (v4f){0.f, 0.f, 0.f, 0.f};

  const int KT = HIDDEN / 64;  // 32 K-tiles

  // prologue: stage tiles 0,1 into bufs 0,1 (6 gld each, tile0 oldest)
#pragma unroll
  for (int tt = 0; tt < 2; ++tt) {
    const int kb = tt * 64;
#pragma unroll
    for (int j = 0; j < 4; ++j)
      gld_lds16(Ag + kb + j * 8 * HIDDEN,
                &lds[tt * 16384 + (w * 4 + j) * 512 + lane * 8]);
#pragma unroll
    for (int j = 0; j < 2; ++j)
      gld_lds16(Bg + kb + j * 8 * HIDDEN,
                &lds[49152 + tt * 8192 + (w * 2 + j) * 512 + lane * 8]);
  }
  asm volatile("s_waitcnt vmcnt(6)" ::: "memory");  // tile 0 landed
  __builtin_amdgcn_s_barrier();

  int b = 0;  // tile kt uses buf kt%3
  for (int kt = 0; kt < KT; ++kt) {
    const int kb2 = kt * 64 + 128;              // K offset of tile kt+2
    const int b2 = (b >= 1) ? b - 1 : 2;        // (kt+2)%3 — was tile kt-1's buf
    const u16t* Asb = &lds[b * 16384];
    const u16t* Bsb = &lds[49152 + b * 8192];
    const bool pre = (kt + 2 < KT);

    // ---------------- phase 1: m-half 0 ----------------
    v8s b0[2], b1[2];
#pragma unroll
    for (int j = 0; j < 2; ++j) {
      const u16t* p = Bsb + (wn * 32 + j * 16 + l15) * 64;
      b0[j] = *(const v8s*)(p + ca0);
      b1[j] = *(const v8s*)(p + ca1);
    }
    v8s a0[4], a1[4];
#pragma unroll
    for (int i = 0; i < 4; ++i) {
      const u16t* p = Asb + (wm * 128 + i * 16 + l15) * 64;
      a0[i] = *(const v8s*)(p + ca0);
      a1[i] = *(const v8s*)(p + ca1);
    }
    if (pre) {
      gld_lds16(Ag + kb2, &lds[b2 * 16384 + (w * 4 + 0) * 512 + lane * 8]);
      gld_lds16(Ag + kb2 + 8 * HIDDEN, &lds[b2 * 16384 + (w * 4 + 1) * 512 + lane * 8]);
      gld_lds16(Bg + kb2, &lds[49152 + b2 * 8192 + (w * 2 + 0) * 512 + lane * 8]);
    }
    __builtin_amdgcn_s_barrier();
    asm volatile("s_waitcnt lgkmcnt(0)" ::: "memory");
    __builtin_amdgcn_s_setprio(1);
#pragma unroll
    for (int i = 0; i < 4; ++i)
#pragma unroll
      for (int j = 0; j < 2; ++j) {
        acc[i][j] = __builtin_amdgcn_mfma_f32_16x16x32_bf16(a0[i], b0[j], acc[i][j], 0, 0, 0);
        acc[i][j] = __builtin_amdgcn_mfma_f32_16x16x32_bf16(a1[i], b1[j], acc[i][j], 0, 0, 0);
      }
    __builtin_amdgcn_s_setprio(0);
    __builtin_amdgcn_s_barrier();

    // ---------------- phase 2: m-half 1 ----------------
#pragma unroll
    for (int i = 0; i < 4; ++i) {
      const u16t* p = Asb + (wm * 128 + 64 + i * 16 + l15) * 64;
      a0[i] = *(const v8s*)(p + ca0);
      a1[i] = *(const v8s*)(p + ca1);
    }
    if (pre) {
      gld_lds16(Ag + kb2 + 16 * HIDDEN, &lds[b2 * 16384 + (w * 4 + 2) * 512 + lane * 8]);
      gld_lds16(Ag + kb2 + 24 * HIDDEN, &lds[b2 * 16384 + (w * 4 + 3) * 512 + lane * 8]);
      gld_lds16(Bg + kb2 + 8 * HIDDEN, &lds[49152 + b2 * 8192 + (w * 2 + 1) * 512 + lane * 8]);
    }
    __builtin_amdgcn_s_barrier();
    asm volatile("s_waitcnt lgkmcnt(0)" ::: "memory");
    __builtin_amdgcn_s_setprio(1);
#pragma unroll
    for (int i = 0; i < 4; ++i)
#pragma unroll
      for (int j = 0; j < 2; ++j) {
        acc[4 + i][j] = __builtin_amdgcn_mfma_f32_16x16x32_bf16(a0[i], b0[j], acc[4 + i][j], 0, 0, 0);
        acc[4 + i][j] = __builtin_amdgcn_mfma_f32_16x16x32_bf16(a1[i], b1[j], acc[4 + i][j], 0, 0, 0);
      }
    __builtin_amdgcn_s_setprio(0);
    // end of K-tile: ensure tile kt+1 landed; keep tile kt+2's 6 loads in flight
    if (pre) {
      asm volatile("s_waitcnt vmcnt(6)" ::: "memory");
    } else if (kt + 1 < KT) {
      asm volatile("s_waitcnt vmcnt(0)" ::: "memory");
    }
    __builtin_amdgcn_s_barrier();
    b = (b == 2) ? 0 : b + 1;
  }

  // ---------------- epilogue ----------------
  if (OUT == 2) {
    // transpose via LDS (reuse staging space), then coalesced 16B stores.
    // __syncthreads (full drain) is safe here: pipeline is already drained.
    u16t* Ct = (u16t*)lds;  // [128 n][264 m] (pad 8)
    __syncthreads();
#pragma unroll
    for (int i = 0; i < 8; ++i)
#pragma unroll
      for (int j = 0; j < 2; ++j)
#pragma unroll
        for (int r = 0; r < 4; ++r)
          Ct[(wn * 32 + j * 16 + l15) * 264 + wm * 128 + i * 16 + quad * 4 + r] =
              f2bf(acc[i][j][r]);
    __syncthreads();
    u16t* VtOut = (u16t*)Cp;
#pragma unroll
    for (int it = 0; it < 8; ++it) {
      int idx = t + it * 512;   // 0..4095
      int nl = idx >> 5;        // 0..127
      int mc = idx & 31;        // 0..31 (16B chunks)
      *(uint4*)&VtOut[(size_t)(n0 + nl) * MROWS + m0 + mc * 8] =
          *(const uint4*)&Ct[nl * 264 + mc * 8];
    }
  } else {
#pragma unroll
    for (int i = 0; i < 8; ++i) {
#pragma unroll
      for (int j = 0; j < 2; ++j) {
        int col = n0 + wn * 32 + j * 16 + l15;
#pragma unroll
        for (int r = 0; r < 4; ++r) {
          int row = m0 + wm * 128 + i * 16 + quad * 4 + r;
          if (OUT == 1)
            ((float*)Cp)[(size_t)row * HIDDEN + col] = acc[i][j][r];
          else
            ((u16t*)Cp)[(size_t)row * HIDDEN + col] = f2bf(acc[i][j][r]);
        }
      }
    }
  }
}

// ---------------------------------------------------------------------------
// Fallback GEMM (m97 structure) for small-workspace path: B is fp32.
// ---------------------------------------------------------------------------
template <int OUT_F32>
__global__ __launch_bounds__(256) void gemm_a16(const u16t* __restrict__ A,
                                                const void* __restrict__ Bp,
                                                void* __restrict__ Cp) {
  __shared__ u16t As[128 * 32];
  __shared__ u16t Bs[128 * 32];

  const int n0 = blockIdx.x * 128;
  const int m0 = blockIdx.y * 128;
  const int t = threadIdx.x;
  const int lane = t & 63;
  const int w = t >> 6;
  const int wm = w & 1;
  const int wn = w >> 1;
  const int l15 = lane & 15;
  const int quad = lane >> 4;

  v4f acc[4][4];
#pragma unroll
  for (int i = 0; i < 4; ++i)
#pragma unroll
    for (int j = 0; j < 4; ++j) acc[i][j] = (v4f){0.f, 0.f, 0.f, 0.f};

  for (int kb = 0; kb < HIDDEN; kb += 32) {
#pragma unroll
    for (int j = 0; j < 2; ++j) {
      int idx = t + j * 256;
      int row = idx >> 2;
      int ch = (idx & 3) * 8;
      gld_lds16(&A[(size_t)(m0 + row) * HIDDEN + kb + ch], &As[idx * 8]);
    }
    {
      const float* B = (const float*)Bp;
#pragma unroll
      for (int j = 0; j < 4; ++j) {
        int idx = t + j * 256;
        int row = idx >> 3;
        int c4 = (idx & 7) * 4;
        float4 bv = *(const float4*)&B[(size_t)(n0 + row) * HIDDEN + kb + c4];
        *(ushort4*)&Bs[row * 32 + c4] = f2bf4(bv);
      }
    }
    __syncthreads();

    v8s af[4], bf[4];
#pragma unroll
    for (int mt = 0; mt < 4; ++mt)
      af[mt] = *(const v8s*)&As[(wm * 64 + mt * 16 + l15) * 32 + quad * 8];
#pragma unroll
    for (int nt = 0; nt < 4; ++nt)
      bf[nt] = *(const v8s*)&Bs[(wn * 64 + nt * 16 + l15) * 32 + quad * 8];

#pragma unroll
    for (int mt = 0; mt < 4; ++mt)
#pragma unroll
      for (int nt = 0; nt < 4; ++nt)
        acc[mt][nt] = __builtin_amdgcn_mfma_f32_16x16x32_bf16(af[mt], bf[nt], acc[mt][nt], 0, 0, 0);
    __syncthreads();
  }

#pragma unroll
  for (int mt = 0; mt < 4; ++mt) {
#pragma unroll
    for (int nt = 0; nt < 4; ++nt) {
      int col = n0 + wn * 64 + nt * 16 + l15;
#pragma unroll
      for (int r = 0; r < 4; ++r) {
        int row = m0 + wm * 64 + mt * 16 + quad * 4 + r;
        if (OUT_F32)
          ((float*)Cp)[(size_t)row * HIDDEN + col] = acc[mt][nt][r];
        else
          ((u16t*)Cp)[(size_t)row * HIDDEN + col] = f2bf(acc[mt][nt][r]);
      }
    }
  }
}

// Fallback V-projection with transposed output (fp32 B).
__global__ __launch_bounds__(256) void gemm_vt_f32(const u16t* __restrict__ A,
                                                   const void* __restrict__ Bp,
                                                   u16t* __restrict__ VtOut) {
  __shared__ u16t As[128 * 32];
  __shared__ u16t Bs[128 * 32];
  __shared__ u16t Ct[128 * 136];

  const int n0 = blockIdx.x * 128;
  const int m0 = blockIdx.y * 128;
  const int t = threadIdx.x;
  const int lane = t & 63;
  const int w = t >> 6;
  const int wm = w & 1;
  const int wn = w >> 1;
  const int l15 = lane & 15;
  const int quad = lane >> 4;

  v4f acc[4][4];
#pragma unroll
  for (int i = 0; i < 4; ++i)
#pragma unroll
    for (int j = 0; j < 4; ++j) acc[i][j] = (v4f){0.f, 0.f, 0.f, 0.f};

  for (int kb = 0; kb < HIDDEN; kb += 32) {
#pragma unroll
    for (int j = 0; j < 2; ++j) {
      int idx = t + j * 256;
      int row = idx >> 2;
      int ch = (idx & 3) * 8;
      gld_lds16(&A[(size_t)(m0 + row) * HIDDEN + kb + ch], &As[idx * 8]);
    }
    {
      const float* B = (const float*)Bp;
#pragma unroll
      for (int j = 0; j < 4; ++j) {
        int idx = t + j * 256;
        int row = idx >> 3;
        int c4 = (idx & 7) * 4;
        float4 bv = *(const float4*)&B[(size_t)(n0 + row) * HIDDEN + kb + c4];
        *(ushort4*)&Bs[row * 32 + c4] = f2bf4(bv);
      }
    }
    __syncthreads();

    v8s af[4], bf[4];
#pragma unroll
    for (int mt = 0; mt < 4; ++mt)
      af[mt] = *(const v8s*)&As[(wm * 64 + mt * 16 + l15) * 32 + quad * 8];
#pragma unroll
    for (int nt = 0; nt < 4; ++nt)
      bf[nt] = *(const v8s*)&Bs[(wn * 64 + nt * 16 + l15) * 32 + quad * 8];

#pragma unroll
    for (int mt = 0; mt < 4; ++mt)
#pragma unroll
      for (int nt = 0; nt < 4; ++nt)
        acc[mt][nt] = __builtin_amdgcn_mfma_f32_16x16x32_bf16(af[mt], bf[nt], acc[mt][nt], 0, 0, 0);
    __syncthreads();
  }

#pragma unroll
  for (int mt = 0; mt < 4; ++mt)
#pragma unroll
    for (int nt = 0; nt < 4; ++nt)
#pragma unroll
      for (int r = 0; r < 4; ++r)
        Ct[(wn * 64 + nt * 16 + l15) * 136 + (wm * 64 + mt * 16 + quad * 4 + r)] =
            f2bf(acc[mt][nt][r]);
  __syncthreads();

#pragma unroll
  for (int j = 0; j < 8; ++j) {
    int idx = t + j * 256;
    int nl = idx >> 4;
    int mc = idx & 15;
    *(uint4*)&VtOut[(size_t)(n0 + nl) * MROWS + m0 + mc * 8] =
        *(const uint4*)&Ct[nl * 136 + mc * 8];
  }
}

// ---------------------------------------------------------------------------
// RoPE in-place on q and k (bf16, [m][h*128+d])   (unchanged)
// ---------------------------------------------------------------------------
__global__ __launch_bounds__(256) void rope_k(u16t* __restrict__ q, u16t* __restrict__ k) {
  int idx = blockIdx.x * 256 + threadIdx.x;
  int i = idx & 63;
  int h = (idx >> 6) & (NHEAD - 1);
  int m = idx >> 10;
  int s = m & (SEQ - 1);
  float inv = __expf(-(float)i * 0.14391156831212787f);
  float th = (float)s * inv;
  float sn, cs;
  __sincosf(th, &sn, &cs);
  size_t base = (size_t)m * HIDDEN + h * HDIM + i;
  {
    float a = bf2f(q[base]), b = bf2f(q[base + 64]);
    q[base] = f2bf(a * cs - b * sn);
    q[base + 64] = f2bf(b * cs + a * sn);
  }
  {
    float a = bf2f(k[base]), b = bf2f(k[base + 64]);
    k[base] = f2bf(a * cs - b * sn);
    k[base + 64] = f2bf(b * cs + a * sn);
  }
}

// ---------------------------------------------------------------------------
// Flash attention v3 (byte-identical to the R1 version that passed).
// ---------------------------------------------------------------------------
__global__ __launch_bounds__(512) void flash2(const u16t* __restrict__ Q,
                                              const u16t* __restrict__ K,
                                              const u16t* __restrict__ Vt,
                                              u16t* __restrict__ O) {
  __shared__ u16t smem[40960];  // 80 KB
  u16t* Ps = smem + 32768;

  const int a = blockIdx.x;
  const int bh = blockIdx.y;
  const int b = bh >> 4;
  const int h = bh & 15;
  const size_t rowb = (size_t)b * SEQ;
  const u16t* vtg = Vt + (size_t)h * HDIM * MROWS + (size_t)b * SEQ;

  const int t = threadIdx.x;
  const int lane = t & 63;
  const int w = t >> 6;
  const int l15 = lane & 15;
  const int quad = lane >> 4;
  const int l7 = l15 & 7;
  const float C2 = 0.12751743f;
  const float NEG = -3.0e38f;

  const int krow = t >> 4;
  const int kch = (t & 15) * 8;
  const int vrow = t >> 3;
  const int vch = (t & 7) * 8;
  const int kx = kch ^ ((krow & 7) * 8);
  const int vx = vch ^ ((vrow & 7) * 8);
  const u16t* Kgb = &K[(rowb + krow) * HIDDEN + h * HDIM + kch];
  const u16t* Vgb = vtg + (size_t)vrow * MROWS + vch;

  for (int half = 0; half < 2; ++half) {
    const int qt = half ? (15 - a) : a;
    const int q0 = qt * 128;
    const int nsteps = 2 * (qt + 1);

    uint4 ck0 = *(const uint4*)Kgb;
    uint4 ck1 = *(const uint4*)(Kgb + 32 * HIDDEN);
    uint4 cv0 = *(const uint4*)Vgb;
    uint4 cv1 = *(const uint4*)(Vgb + (size_t)64 * MROWS);

#pragma unroll
    for (int j = 0; j < 4; ++j) {
      int idx = t + j * 512;
      int row = idx >> 4;
      int ch = (idx & 15) * 8;
      *(uint4*)&smem[row * 136 + ch] =
          *(const uint4*)&Q[(rowb + q0 + row) * HIDDEN + h * HDIM + ch];
    }
    __syncthreads();
    v8s qf[4];
#pragma unroll
    for (int ks = 0; ks < 4; ++ks)
      qf[ks] = *(const v8s*)&smem[(w * 16 + l15) * 136 + ks * 32 + quad * 8];
    __syncthreads();

    float mi[4], li[4];
    v4f o[8];
#pragma unroll
    for (int r = 0; r < 4; ++r) { mi[r] = NEG; li[r] = 0.f; }
#pragma unroll
    for (int nt = 0; nt < 8; ++nt) o[nt] = (v4f){0.f, 0.f, 0.f, 0.f};

    for (int kt = 0; kt < nsteps; ++kt) {
      u16t* Kb = smem + (kt & 1) * 16384;
      u16t* Vb = Kb + 8192;
      *(uint4*)&Kb[krow * 128 + kx] = ck0;
      *(uint4*)&Kb[(krow + 32) * 128 + kx] = ck1;
      *(uint4*)&Vb[vrow * 64 + vx] = cv0;
      *(uint4*)&Vb[(vrow + 64) * 64 + vx] = cv1;
      if (kt + 1 < nsteps) {
        const int kv1 = (kt + 1) * 64;
        const u16t* kg = Kgb + (size_t)kv1 * HIDDEN;
        ck0 = *(const uint4*)kg;
        ck1 = *(const uint4*)(kg + 32 * HIDDEN);
        const u16t* vg = Vgb + kv1;
        cv0 = *(const uint4*)vg;
        cv1 = *(const uint4*)(vg + (size_t)64 * MROWS);
      }
      __syncthreads();

      const int kv0 = kt * 64;
      v4f sc[4];
#pragma unroll
      for (int nt = 0; nt < 4; ++nt) {
        sc[nt] = (v4f){0.f, 0.f, 0.f, 0.f};
#pragma unroll
        for (int ks = 0; ks < 4; ++ks) {
          v8s kf = *(const v8s*)&Kb[(nt * 16 + l15) * 128 +
                                    ((ks * 32 + quad * 8) ^ (l7 * 8))];
          sc[nt] = __builtin_amdgcn_mfma_f32_16x16x32_bf16(qf[ks], kf, sc[nt], 0, 0, 0);
        }
      }

      const bool mm = (kv0 + 64 > q0);
#pragma unroll
      for (int r = 0; r < 4; ++r) {
        float sv[4];
#pragma unroll
        for (int nt = 0; nt < 4; ++nt) sv[nt] = sc[nt][r];
        if (mm) {
          int row_g = q0 + w * 16 + quad * 4 + r;
#pragma unroll
          for (int nt = 0; nt < 4; ++nt)
            if (kv0 + nt * 16 + l15 > row_g) sv[nt] = NEG;
        }
        float rm = fmaxf(fmaxf(sv[0], sv[1]), fmaxf(sv[2], sv[3]));
#pragma unroll
        for (int off = 1; off < 16; off <<= 1) rm = fmaxf(rm, __shfl_xor(rm, off));
        float mn = fmaxf(mi[r], rm);
        float alpha = exp2f((mi[r] - mn) * C2);
        float ps = 0.f;
        u16t pb[4];
#pragma unroll
        for (int nt = 0; nt < 4; ++nt) {
          float p = exp2f((sv[nt] - mn) * C2);
          ps += p;
          pb[nt] = f2bf(p);
        }
#pragma unroll
        for (int off = 1; off < 16; off <<= 1) ps += __shfl_xor(ps, off);
        li[r] = li[r] * alpha + ps;
        mi[r] = mn;
#pragma unroll
        for (int nt = 0; nt < 8; ++nt) o[nt][r] *= alpha;
        int rowp = w * 16 + quad * 4 + r;
        int psw = (rowp & 7) * 8;
#pragma unroll
        for (int nt = 0; nt < 4; ++nt)
          Ps[rowp * 64 + ((nt * 16 + l15) ^ psw)] = pb[nt];
      }

#pragma unroll
      for (int ks = 0; ks < 2; ++ks) {
        v8s pf = *(const v8s*)&Ps[(w * 16 + l15) * 64 +
                                  ((ks * 32 + quad * 8) ^ (l7 * 8))];
#pragma unroll
        for (int nt = 0; nt < 8; ++nt) {
          v8s vf = *(const v8s*)&Vb[(nt * 16 + l15) * 64 +
                                    ((ks * 32 + quad * 8) ^ (l7 * 8))];
          o[nt] = __builtin_amdgcn_mfma_f32_16x16x32_bf16(pf, vf, o[nt], 0, 0, 0);
        }
      }
    }

#pragma unroll
    for (int r = 0; r < 4; ++r) {
      float inv = 1.0f / li[r];
      size_t row = rowb + q0 + w * 16 + quad * 4 + r;
#pragma unroll
      for (int nt = 0; nt < 8; ++nt)
        O[row * HIDDEN + h * HDIM + nt * 16 + l15] = f2bf(o[nt][r] * inv);
    }
    __syncthreads();
  }
}

// ---------------------------------------------------------------------------
extern "C" void kernel_launch(void* const* d_in, const int* in_sizes, int n_in,
                              void* d_out, int out_size, void* d_ws, size_t ws_size,
                              hipStream_t stream) {
  const float* X = (const float*)d_in[0];
  const float* Wq = (const float*)d_in[3];
  const float* Wk = (const float*)d_in[4];
  const float* Wv = (const float*)d_in[5];
  const float* Wo = (const float*)d_in[6];
  float* out = (float*)d_out;

  char* wsb = (char*)d_ws;
  const size_t MB = 1024 * 1024;
  u16t* xb = (u16t*)(wsb + 0 * MB);    // 16 MB, dead after QKV gemms
  u16t* q = (u16t*)(wsb + 16 * MB);    // 16 MB
  u16t* k = (u16t*)(wsb + 32 * MB);    // 16 MB
  u16t* vt = (u16t*)(wsb + 48 * MB);   // 16 MB
  u16t* a = xb;                        // flash out aliases xb (xb dead by then)

  dim3 blk(256);
  dim3 fg(8, BATCH * NHEAD);
  const int XN8 = MROWS * HIDDEN / 8;   // 1M
  const int WN8 = HIDDEN * HIDDEN / 8;  // 512K (= 2^19)

  cvt_bf16<<<(XN8 + 255) / 256, blk, 0, stream>>>(X, xb, XN8);

  if (ws_size >= 96 * MB) {
    u16t* wqb = (u16t*)(wsb + 64 * MB);
    u16t* wkb = (u16t*)(wsb + 72 * MB);
    u16t* wvb = (u16t*)(wsb + 80 * MB);
    u16t* wob = (u16t*)(wsb + 88 * MB);
    cvt_bf16_w4<<<(4 * WN8) / 256, blk, 0, stream>>>(Wq, Wk, Wv, Wo, wqb, wkb, wvb, wob);

    dim3 g8(HIDDEN / 128, MROWS / 256);  // (16, 16) = 256 WGs
    gemm8p<0><<<g8, dim3(512), 0, stream>>>(xb, wqb, q);
    gemm8p<0><<<g8, dim3(512), 0, stream>>>(xb, wkb, k);
    gemm8p<2><<<g8, dim3(512), 0, stream>>>(xb, wvb, vt);
    rope_k<<<(MROWS * NHEAD * 64) / 256, blk, 0, stream>>>(q, k);
    flash2<<<fg, dim3(512), 0, stream>>>(q, k, vt, a);
    gemm8p<1><<<g8, dim3(512), 0, stream>>>(a, wob, out);
  } else {
    dim3 gg(HIDDEN / 128, MROWS / 128);  // (16, 32)
    gemm_a16<0><<<gg, blk, 0, stream>>>(xb, Wq, q);
    gemm_a16<0><<<gg, blk, 0, stream>>>(xb, Wk, k);
    gemm_vt_f32<<<gg, blk, 0, stream>>>(xb, Wv, vt);
    rope_k<<<(MROWS * NHEAD * 64) / 256, blk, 0, stream>>>(q, k);
    flash2<<<fg, dim3(512), 0, stream>>>(q, k, vt, a);
    gemm_a16<1><<<gg, blk, 0, stream>>>(a, Wo, out);
  }
}